// Round 5
// baseline (397.917 us; speedup 1.0000x reference)
//
#include <hip/hip_runtime.h>
#include <stdint.h>

// Problem dims (fixed)
constexpr int T_DIM   = 16384;
constexpr int IN_DIM  = 4096;
constexpr int OUT_DIM = 4096;

using int32x4 = __attribute__((ext_vector_type(4))) int;

#define GLOAD_LDS16(g, l)                                                     \
    __builtin_amdgcn_global_load_lds(                                         \
        (const __attribute__((address_space(1))) void*)(uintptr_t)(g),        \
        (__attribute__((address_space(3))) void*)(uintptr_t)(l), 16, 0, 0)

// ===========================================================================
// Pre-pass: int32 (int8-valued) -> packed int8, pre-swizzled: within each
// 64-B group of 4 chunks, stored = chunk ^ ((row>>1)&3).  (rule #21)
// ===========================================================================
__global__ void pack_swz(const int* __restrict__ src, int8_t* __restrict__ dst,
                         int rows, int cols) {
    int64_t tid = (int64_t)blockIdx.x * blockDim.x + threadIdx.x;
    int64_t nchunks = (int64_t)rows * (cols / 16);
    if (tid >= nchunks) return;
    int row  = (int)(tid / (cols / 16));
    int cidx = (int)(tid % (cols / 16));
    const int32x4* s4 =
        reinterpret_cast<const int32x4*>(src + (int64_t)row * cols + (cidx << 4));
    uint32_t p[4];
#pragma unroll
    for (int v = 0; v < 4; ++v) {
        int32x4 t = s4[v];
        p[v] = (uint32_t)(t[0] & 0xff) | ((uint32_t)(t[1] & 0xff) << 8) |
               ((uint32_t)(t[2] & 0xff) << 16) | ((uint32_t)(t[3] & 0xff) << 24);
    }
    int cs = (cidx & ~3) | ((cidx & 3) ^ ((row >> 1) & 3));
    *reinterpret_cast<int32x4*>(dst + (int64_t)row * cols + (cs << 4)) =
        *reinterpret_cast<int32x4*>(p);
}

// ===========================================================================
// Main GEMM: 256x256 tile, BK=64 int8, 8 waves (2Mx4N), per-wave 128x64.
// 4-buffer LDS pipeline (128 KiB), counted vmcnt(8), and — new this round —
// 4 SMALL phases per K-tile (8 MFMA each, template grain per m196/m201):
//   P0 {bf01+af0-3 | gloadA.0 | bar lgkm | 8 MFMA m0-3 n0-1 | bar}
//   P1 {bf23       | gloadA.1 | bar lgkm | 8 MFMA m0-3 n2-3 | bar}
//   P2 {af4-7      | gloadB.0 | bar lgkm | 8 MFMA m4-7 n0-1 | bar}
//   P3 {           | gloadB.1 | bar      | 8 MFMA m4-7 n2-3 | vmcnt(8) bar}
// ===========================================================================
constexpr int BM = 256, BN = 256, BK = 64;
constexpr int NT    = IN_DIM / BK;     // 64
constexpr int ATILE = BM * BK;         // 16 KiB
constexpr int BUFSZ = 2 * ATILE;       // 32 KiB (A + B)

__global__ __launch_bounds__(512, 2)
void gemm_i8_8p(const int8_t* __restrict__ x8, const int8_t* __restrict__ w8,
                const int* __restrict__ bias, const float* __restrict__ alphap,
                const float* __restrict__ betap, int* __restrict__ out) {
    __shared__ __align__(16) int8_t lds[4 * BUFSZ];   // 128 KiB

    const int tid  = threadIdx.x;
    const int lane = tid & 63;
    const int wid  = tid >> 6;
    const int wr   = wid >> 2;   // 0..1
    const int wc   = wid & 3;    // 0..3

    // XCD-chunked bijective swizzle (nwg = 1024, %8==0)
    const int nwg = gridDim.x;
    const int cpx = nwg >> 3;
    const int bid = blockIdx.x;
    const int swz = (bid & 7) * cpx + (bid >> 3);
    const int bm  = swz >> 4;    // 64 M-blocks
    const int bn  = swz & 15;    // 16 N-blocks
    const int brow = bm * BM;
    const int bcol = bn * BN;

    const float alpha = *alphap;
    const float beta  = *betap;

    const int g = lane >> 4;     // K-chunk 0..3 (16 int8 each)
    const int r = lane & 15;

    // one 16B global_load_lds of tile kt's A (resp. B) half `l` (0/1)
    auto stageA1 = [&](int kt, int8_t* buf, int l) {
        const int off = l * 8192 + tid * 16;
        const int row = off >> 6;
        GLOAD_LDS16(x8 + (int64_t)(brow + row) * IN_DIM + kt * BK + (off & 63),
                    buf + off);
    };
    auto stageB1 = [&](int kt, int8_t* buf, int l) {
        const int off = l * 8192 + tid * 16;
        const int row = off >> 6;
        GLOAD_LDS16(w8 + (int64_t)(bcol + row) * IN_DIM + kt * BK + (off & 63),
                    buf + ATILE + off);
    };
    auto ldA = [&](const int8_t* Ab, int m) -> int32x4 {
        const int row = wr * 128 + m * 16 + r;
        const int sc  = g ^ ((row >> 1) & 3);
        return *reinterpret_cast<const int32x4*>(Ab + row * BK + (sc << 4));
    };
    auto ldB = [&](const int8_t* Bb, int n) -> int32x4 {
        const int row = wc * 64 + n * 16 + r;
        const int sc  = g ^ ((row >> 1) & 3);
        return *reinterpret_cast<const int32x4*>(Bb + row * BK + (sc << 4));
    };

    int32x4 acc[8][4] = {};

#define MFMA8(M0, N0)                                                          \
    _Pragma("unroll") for (int m = 0; m < 4; ++m)                              \
        _Pragma("unroll") for (int n = 0; n < 2; ++n)                          \
            acc[(M0) + m][(N0) + n] = __builtin_amdgcn_mfma_i32_16x16x64_i8(   \
                af[(M0) + m], bf[(N0) + n], acc[(M0) + m][(N0) + n], 0, 0, 0);

    // One K-tile: 4 small phases. VM: 8 = steady, 4/0 = drain, -1 = none.
#define KTILE(T, BIDX, PF, VM)                                                 \
    do {                                                                       \
        const int8_t* Ab = lds + (BIDX) * BUFSZ;                               \
        const int8_t* Bb = Ab + ATILE;                                         \
        int8_t* nxt = lds + (((BIDX) + 3) & 3) * BUFSZ;                        \
        int32x4 af[8], bf[4];                                                  \
        /* P0 */                                                               \
        bf[0] = ldB(Bb, 0); bf[1] = ldB(Bb, 1);                                \
        _Pragma("unroll") for (int m = 0; m < 4; ++m) af[m] = ldA(Ab, m);      \
        if (PF) stageA1((T) + 3, nxt, 0);                                      \
        __builtin_amdgcn_s_barrier();                                          \
        asm volatile("s_waitcnt lgkmcnt(0)");                                  \
        __builtin_amdgcn_s_setprio(1);                                         \
        MFMA8(0, 0)                                                            \
        __builtin_amdgcn_s_setprio(0);                                         \
        __builtin_amdgcn_s_barrier();                                          \
        /* P1 */                                                               \
        bf[2] = ldB(Bb, 2); bf[3] = ldB(Bb, 3);                                \
        if (PF) stageA1((T) + 3, nxt, 1);                                      \
        __builtin_amdgcn_s_barrier();                                          \
        asm volatile("s_waitcnt lgkmcnt(0)");                                  \
        __builtin_amdgcn_s_setprio(1);                                         \
        MFMA8(0, 2)                                                            \
        __builtin_amdgcn_s_setprio(0);                                         \
        __builtin_amdgcn_s_barrier();                                          \
        /* P2 */                                                               \
        _Pragma("unroll") for (int m = 0; m < 4; ++m) af[4 + m] = ldA(Ab, 4 + m); \
        if (PF) stageB1((T) + 3, nxt, 0);                                      \
        __builtin_amdgcn_s_barrier();                                          \
        asm volatile("s_waitcnt lgkmcnt(0)");                                  \
        __builtin_amdgcn_s_setprio(1);                                         \
        MFMA8(4, 0)                                                            \
        __builtin_amdgcn_s_setprio(0);                                         \
        __builtin_amdgcn_s_barrier();                                          \
        /* P3 */                                                               \
        if (PF) stageB1((T) + 3, nxt, 1);                                      \
        __builtin_amdgcn_s_barrier();                                          \
        __builtin_amdgcn_s_setprio(1);                                         \
        MFMA8(4, 2)                                                            \
        __builtin_amdgcn_s_setprio(0);                                         \
        if ((VM) == 8)      asm volatile("s_waitcnt vmcnt(8)" ::: "memory");   \
        else if ((VM) == 4) asm volatile("s_waitcnt vmcnt(4)" ::: "memory");   \
        else if ((VM) == 0) asm volatile("s_waitcnt vmcnt(0)" ::: "memory");   \
        __builtin_amdgcn_s_barrier();                                          \
        asm volatile("" ::: "memory"); /* pin stage/reads below boundary */    \
    } while (0)

    // Prologue: tiles 0,1,2 in flight; wait until tile 0 landed.
    stageA1(0, lds, 0);            stageA1(0, lds, 1);
    stageB1(0, lds, 0);            stageB1(0, lds, 1);
    stageA1(1, lds + BUFSZ, 0);    stageA1(1, lds + BUFSZ, 1);
    stageB1(1, lds + BUFSZ, 0);    stageB1(1, lds + BUFSZ, 1);
    stageA1(2, lds + 2*BUFSZ, 0);  stageA1(2, lds + 2*BUFSZ, 1);
    stageB1(2, lds + 2*BUFSZ, 0);  stageB1(2, lds + 2*BUFSZ, 1);
    asm volatile("s_waitcnt vmcnt(8)" ::: "memory");
    __builtin_amdgcn_s_barrier();
    asm volatile("" ::: "memory");

    // Main loop: buffer indices are literals (tt % 4 == 0).
#pragma unroll 1
    for (int tt = 0; tt < NT - 4; tt += 4) {
        KTILE(tt + 0, 0, true, 8);
        KTILE(tt + 1, 1, true, 8);
        KTILE(tt + 2, 2, true, 8);
        KTILE(tt + 3, 3, true, 8);
    }
    // Tail: tiles 60..63 (stage 63 during 60; drain 8->4->0).
    KTILE(NT - 4, 0, true,  8);
    KTILE(NT - 3, 1, false, 4);
    KTILE(NT - 2, 2, false, 0);
    KTILE(NT - 1, 3, false, -1);
#undef KTILE
#undef MFMA8

    // Epilogue: y = acc*alpha + bias*beta, round, clip, store int32.
    // C/D: col = lane&15, row = (lane>>4)*4 + j.
    const int r4 = (lane >> 4) * 4;
    const int cl = lane & 15;
#pragma unroll
    for (int n = 0; n < 4; ++n) {
        const int col = bcol + wc * 64 + n * 16 + cl;
        const float bterm = (float)bias[col] * beta;
#pragma unroll
        for (int m = 0; m < 8; ++m) {
            const int row0 = brow + wr * 128 + m * 16 + r4;
#pragma unroll
            for (int j = 0; j < 4; ++j) {
                float y = (float)acc[m][n][j] * alpha + bterm;
                y = rintf(y);
                y = fminf(fmaxf(y, -128.0f), 127.0f);
                out[(int64_t)(row0 + j) * OUT_DIM + col] = (int)y;
            }
        }
    }
}

// ===========================================================================
// Fallback (ws too small): reads int32 inputs directly, packs in regs,
// swizzled ds_write. 128x128 tile. Known-correct (round 2).
// ===========================================================================
__global__ __launch_bounds__(256)
void gemm_i8_fb(const int* __restrict__ x32, const int* __restrict__ w32,
                const int* __restrict__ bias, const float* __restrict__ alphap,
                const float* __restrict__ betap, int* __restrict__ out) {
    constexpr int FBM = 128, FBK = 128;
    __shared__ int8_t lA[FBM * FBK];
    __shared__ int8_t lB[FBM * FBK];

    const int tid  = threadIdx.x;
    const int wid  = tid >> 6;
    const int lane = tid & 63;
    const int nwg = gridDim.x;
    const int cpx = nwg >> 3;
    const int bid = blockIdx.x;
    const int swz = (bid & 7) * cpx + (bid >> 3);
    const int brow = (swz >> 5) * FBM;
    const int bcol = (swz & 31) * FBM;
    const int wr = wid >> 1, wc = wid & 1;
    const float alpha = *alphap;
    const float beta  = *betap;

    int32x4 acc[4][4] = {};
    for (int kt = 0; kt < IN_DIM / FBK; ++kt) {
        const int64_t kbase = (int64_t)kt * FBK;
#pragma unroll
        for (int q = 0; q < 4; ++q) {
            const int off = wid * 4096 + q * 1024 + lane * 16;
            const int row = off >> 7;
            const int k   = off & 127;
            const int* ga = x32 + (int64_t)(brow + row) * IN_DIM + kbase + k;
            const int* gb = w32 + (int64_t)(bcol + row) * IN_DIM + kbase + k;
            uint32_t pa[4], pb[4];
#pragma unroll
            for (int v = 0; v < 4; ++v) {
                int32x4 ta = reinterpret_cast<const int32x4*>(ga)[v];
                int32x4 tb = reinterpret_cast<const int32x4*>(gb)[v];
                pa[v] = (uint32_t)(ta[0] & 0xff) | ((uint32_t)(ta[1] & 0xff) << 8) |
                        ((uint32_t)(ta[2] & 0xff) << 16) | ((uint32_t)(ta[3] & 0xff) << 24);
                pb[v] = (uint32_t)(tb[0] & 0xff) | ((uint32_t)(tb[1] & 0xff) << 8) |
                        ((uint32_t)(tb[2] & 0xff) << 16) | ((uint32_t)(tb[3] & 0xff) << 24);
            }
            const int sc = ((k >> 4) ^ (row & 7)) << 4;
            *reinterpret_cast<int32x4*>(lA + row * FBK + sc) = *reinterpret_cast<int32x4*>(pa);
            *reinterpret_cast<int32x4*>(lB + row * FBK + sc) = *reinterpret_cast<int32x4*>(pb);
        }
        __syncthreads();
#pragma unroll
        for (int ks = 0; ks < 2; ++ks) {
            const int gg = lane >> 4, rr = lane & 15;
            const int lc = ks * 4 + gg;
            int32x4 af[4], bf[4];
#pragma unroll
            for (int m = 0; m < 4; ++m) {
                const int row = wr * 64 + m * 16 + rr;
                af[m] = *reinterpret_cast<const int32x4*>(lA + row * FBK + ((lc ^ (row & 7)) << 4));
            }
#pragma unroll
            for (int n = 0; n < 4; ++n) {
                const int row = wc * 64 + n * 16 + rr;
                bf[n] = *reinterpret_cast<const int32x4*>(lB + row * FBK + ((lc ^ (row & 7)) << 4));
            }
#pragma unroll
            for (int m = 0; m < 4; ++m)
#pragma unroll
                for (int n = 0; n < 4; ++n)
                    acc[m][n] = __builtin_amdgcn_mfma_i32_16x16x64_i8(af[m], bf[n], acc[m][n], 0, 0, 0);
        }
        __syncthreads();
    }
    const int r4 = (lane >> 4) * 4;
    const int cl = lane & 15;
#pragma unroll
    for (int n = 0; n < 4; ++n) {
        const int col = bcol + wc * 64 + n * 16 + cl;
        const float bterm = (float)bias[col] * beta;
#pragma unroll
        for (int m = 0; m < 4; ++m) {
            const int row0 = brow + wr * 64 + m * 16 + r4;
#pragma unroll
            for (int j = 0; j < 4; ++j) {
                float y = (float)acc[m][n][j] * alpha + bterm;
                y = rintf(y);
                y = fminf(fmaxf(y, -128.0f), 127.0f);
                out[(int64_t)(row0 + j) * OUT_DIM + col] = (int)y;
            }
        }
    }
}

// ===========================================================================
extern "C" void kernel_launch(void* const* d_in, const int* in_sizes, int n_in,
                              void* d_out, int out_size, void* d_ws, size_t ws_size,
                              hipStream_t stream) {
    const int*   x     = (const int*)d_in[0];
    const int*   w     = (const int*)d_in[1];
    const int*   bias  = (const int*)d_in[2];
    const float* alpha = (const float*)d_in[3];
    const float* beta  = (const float*)d_in[4];
    int*         out   = (int*)d_out;

    const size_t need = (size_t)T_DIM * IN_DIM + (size_t)OUT_DIM * IN_DIM;

    if (ws_size >= need) {
        int8_t* x8 = (int8_t*)d_ws;
        int8_t* w8 = x8 + (size_t)T_DIM * IN_DIM;
        {
            int64_t nch = (int64_t)T_DIM * (IN_DIM / 16);
            pack_swz<<<(int)((nch + 255) / 256), 256, 0, stream>>>(x, x8, T_DIM, IN_DIM);
        }
        {
            int64_t nch = (int64_t)OUT_DIM * (IN_DIM / 16);
            pack_swz<<<(int)((nch + 255) / 256), 256, 0, stream>>>(w, w8, OUT_DIM, IN_DIM);
        }
        const int grid = (T_DIM / BM) * (OUT_DIM / BN);  // 1024
        gemm_i8_8p<<<grid, 512, 0, stream>>>(x8, w8, bias, alpha, beta, out);
    } else {
        const int grid = (T_DIM / 128) * (OUT_DIM / 128);  // 4096
        gemm_i8_fb<<<grid, 256, 0, stream>>>(x, w, bias, alpha, beta, out);
    }
}

// Round 6
// 394.583 us; speedup vs baseline: 1.0084x; 1.0084x over previous
//
#include <hip/hip_runtime.h>
#include <stdint.h>

// Problem dims (fixed)
constexpr int T_DIM   = 16384;
constexpr int IN_DIM  = 4096;
constexpr int OUT_DIM = 4096;

using int32x4 = __attribute__((ext_vector_type(4))) int;

#define GLOAD_LDS16(g, l)                                                     \
    __builtin_amdgcn_global_load_lds(                                         \
        (const __attribute__((address_space(1))) void*)(uintptr_t)(g),        \
        (__attribute__((address_space(3))) void*)(uintptr_t)(l), 16, 0, 0)

// ===========================================================================
// Pre-pass: int32 (int8-valued) -> packed int8, pre-swizzled: within each
// 64-B group of 4 chunks, stored = chunk ^ ((row>>1)&3).  (rule #21)
// ===========================================================================
__global__ void pack_swz(const int* __restrict__ src, int8_t* __restrict__ dst,
                         int rows, int cols) {
    int64_t tid = (int64_t)blockIdx.x * blockDim.x + threadIdx.x;
    int64_t nchunks = (int64_t)rows * (cols / 16);
    if (tid >= nchunks) return;
    int row  = (int)(tid / (cols / 16));
    int cidx = (int)(tid % (cols / 16));
    const int32x4* s4 =
        reinterpret_cast<const int32x4*>(src + (int64_t)row * cols + (cidx << 4));
    uint32_t p[4];
#pragma unroll
    for (int v = 0; v < 4; ++v) {
        int32x4 t = s4[v];
        p[v] = (uint32_t)(t[0] & 0xff) | ((uint32_t)(t[1] & 0xff) << 8) |
               ((uint32_t)(t[2] & 0xff) << 16) | ((uint32_t)(t[3] & 0xff) << 24);
    }
    int cs = (cidx & ~3) | ((cidx & 3) ^ ((row >> 1) & 3));
    *reinterpret_cast<int32x4*>(dst + (int64_t)row * cols + (cs << 4)) =
        *reinterpret_cast<int32x4*>(p);
}

// ===========================================================================
// Main GEMM: 256x256 tile, BK=64 int8, 8 waves (2Mx4N), per-wave 128x64.
// 4-buffer LDS pipeline (128 KiB), counted vmcnt(8).
// THIS ROUND: minimal-sync tile body. NO intra-tile barriers, NO manual
// lgkmcnt — all 12 ds_reads + 4 stages issued at tile top; the compiler's
// own counted lgkmcnt interleaves reads with MFMA; waves drift within the
// tile so ds_read drain overlaps the SIMD partner's MFMA. One boundary
// {vmcnt(8); s_barrier; compiler-fence} per tile (T3 minimum + T4 counted).
// Correctness: reads hit buf t&3 (complete at last boundary); stages hit
// (t+3)&3 whose readers (tile t-1) all drained before the last boundary.
// ===========================================================================
constexpr int BM = 256, BN = 256, BK = 64;
constexpr int NT    = IN_DIM / BK;     // 64
constexpr int ATILE = BM * BK;         // 16 KiB
constexpr int BUFSZ = 2 * ATILE;       // 32 KiB (A + B)

__global__ __launch_bounds__(512, 2)
void gemm_i8_8p(const int8_t* __restrict__ x8, const int8_t* __restrict__ w8,
                const int* __restrict__ bias, const float* __restrict__ alphap,
                const float* __restrict__ betap, int* __restrict__ out) {
    __shared__ __align__(16) int8_t lds[4 * BUFSZ];   // 128 KiB

    const int tid  = threadIdx.x;
    const int lane = tid & 63;
    const int wid  = tid >> 6;
    const int wr   = wid >> 2;   // 0..1
    const int wc   = wid & 3;    // 0..3

    // XCD-chunked bijective swizzle (nwg = 1024, %8==0)
    const int nwg = gridDim.x;
    const int cpx = nwg >> 3;
    const int bid = blockIdx.x;
    const int swz = (bid & 7) * cpx + (bid >> 3);
    const int bm  = swz >> 4;    // 64 M-blocks
    const int bn  = swz & 15;    // 16 N-blocks
    const int brow = bm * BM;
    const int bcol = bn * BN;

    const float alpha = *alphap;
    const float beta  = *betap;

    const int g = lane >> 4;     // K-chunk 0..3 (16 int8 each)
    const int r = lane & 15;

    // ---- hoisted staging addresses: 4 moving global pointers (+BK per
    // staged tile) and 4 fixed LDS destination offsets.
    const int offL0 = tid * 16;            // half 0: rows 0..127
    const int offL1 = 8192 + tid * 16;     // half 1: rows 128..255
    const int rowL0 = offL0 >> 6, inL0 = offL0 & 63;
    const int rowL1 = offL1 >> 6, inL1 = offL1 & 63;
    const int8_t* pA0 = x8 + (int64_t)(brow + rowL0) * IN_DIM + inL0;
    const int8_t* pA1 = x8 + (int64_t)(brow + rowL1) * IN_DIM + inL1;
    const int8_t* pB0 = w8 + (int64_t)(bcol + rowL0) * IN_DIM + inL0;
    const int8_t* pB1 = w8 + (int64_t)(bcol + rowL1) * IN_DIM + inL1;
    const int dA0 = offL0, dA1 = offL1;
    const int dB0 = ATILE + offL0, dB1 = ATILE + offL1;

    // ---- hoisted fragment byte-offsets (buffer-invariant; swizzle baked in)
    int aoff[8], boff[4];
#pragma unroll
    for (int m = 0; m < 8; ++m) {
        const int row = wr * 128 + m * 16 + r;
        aoff[m] = row * BK + ((g ^ ((row >> 1) & 3)) << 4);
    }
#pragma unroll
    for (int n = 0; n < 4; ++n) {
        const int row = wc * 64 + n * 16 + r;
        boff[n] = ATILE + row * BK + ((g ^ ((row >> 1) & 3)) << 4);
    }

    int32x4 acc[8][4] = {};

    // One K-tile, minimal sync. VM: 8 = steady, 4/0 = drain, -1 = none.
#define KTILE(BIDX, PF, VM)                                                    \
    do {                                                                       \
        const int8_t* buf = lds + (BIDX) * BUFSZ;                              \
        int8_t* nxt = lds + (((BIDX) + 3) & 3) * BUFSZ;                        \
        if (PF) {                                                              \
            GLOAD_LDS16(pA0, nxt + dA0);  GLOAD_LDS16(pA1, nxt + dA1);         \
            GLOAD_LDS16(pB0, nxt + dB0);  GLOAD_LDS16(pB1, nxt + dB1);         \
            pA0 += BK; pA1 += BK; pB0 += BK; pB1 += BK;                        \
        }                                                                      \
        int32x4 af[8], bf[4];                                                  \
        _Pragma("unroll") for (int n = 0; n < 4; ++n)                          \
            bf[n] = *reinterpret_cast<const int32x4*>(buf + boff[n]);          \
        _Pragma("unroll") for (int m = 0; m < 8; ++m)                          \
            af[m] = *reinterpret_cast<const int32x4*>(buf + aoff[m]);          \
        __builtin_amdgcn_s_setprio(1);                                         \
        _Pragma("unroll") for (int m = 0; m < 8; ++m)                          \
            _Pragma("unroll") for (int n = 0; n < 4; ++n)                      \
                acc[m][n] = __builtin_amdgcn_mfma_i32_16x16x64_i8(             \
                    af[m], bf[n], acc[m][n], 0, 0, 0);                         \
        __builtin_amdgcn_s_setprio(0);                                         \
        if ((VM) == 8)      asm volatile("s_waitcnt vmcnt(8)" ::: "memory");   \
        else if ((VM) == 4) asm volatile("s_waitcnt vmcnt(4)" ::: "memory");   \
        else if ((VM) == 0) asm volatile("s_waitcnt vmcnt(0)" ::: "memory");   \
        __builtin_amdgcn_s_barrier();                                          \
        asm volatile("" ::: "memory"); /* acquire: pin next tile below */      \
    } while (0)

    // Prologue: stage tiles 0,1,2 (pointers advance to column 3*BK).
#pragma unroll
    for (int t = 0; t < 3; ++t) {
        int8_t* buf = lds + t * BUFSZ;
        GLOAD_LDS16(pA0, buf + dA0);  GLOAD_LDS16(pA1, buf + dA1);
        GLOAD_LDS16(pB0, buf + dB0);  GLOAD_LDS16(pB1, buf + dB1);
        pA0 += BK; pA1 += BK; pB0 += BK; pB1 += BK;
    }
    asm volatile("s_waitcnt vmcnt(8)" ::: "memory");
    __builtin_amdgcn_s_barrier();
    asm volatile("" ::: "memory");

    // Main loop: buffer indices are literals (4-tile unroll).
#pragma unroll 1
    for (int tt = 0; tt < NT - 4; tt += 4) {
        KTILE(0, true, 8);
        KTILE(1, true, 8);
        KTILE(2, true, 8);
        KTILE(3, true, 8);
    }
    // Tail: tiles 60..63 (stage 63 during 60; drain 8->4->0).
    KTILE(0, true,  8);
    KTILE(1, false, 4);
    KTILE(2, false, 0);
    KTILE(3, false, -1);
#undef KTILE

    // Epilogue: y = acc*alpha + bias*beta, round, clip, store int32.
    // C/D: col = lane&15, row = (lane>>4)*4 + j.
    const int r4 = (lane >> 4) * 4;
    const int cl = lane & 15;
#pragma unroll
    for (int n = 0; n < 4; ++n) {
        const int col = bcol + wc * 64 + n * 16 + cl;
        const float bterm = (float)bias[col] * beta;
#pragma unroll
        for (int m = 0; m < 8; ++m) {
            const int row0 = brow + wr * 128 + m * 16 + r4;
#pragma unroll
            for (int j = 0; j < 4; ++j) {
                float y = (float)acc[m][n][j] * alpha + bterm;
                y = rintf(y);
                y = fminf(fmaxf(y, -128.0f), 127.0f);
                out[(int64_t)(row0 + j) * OUT_DIM + col] = (int)y;
            }
        }
    }
}

// ===========================================================================
// Fallback (ws too small): reads int32 inputs directly, packs in regs,
// swizzled ds_write. 128x128 tile. Known-correct (round 2).
// ===========================================================================
__global__ __launch_bounds__(256)
void gemm_i8_fb(const int* __restrict__ x32, const int* __restrict__ w32,
                const int* __restrict__ bias, const float* __restrict__ alphap,
                const float* __restrict__ betap, int* __restrict__ out) {
    constexpr int FBM = 128, FBK = 128;
    __shared__ int8_t lA[FBM * FBK];
    __shared__ int8_t lB[FBM * FBK];

    const int tid  = threadIdx.x;
    const int wid  = tid >> 6;
    const int lane = tid & 63;
    const int nwg = gridDim.x;
    const int cpx = nwg >> 3;
    const int bid = blockIdx.x;
    const int swz = (bid & 7) * cpx + (bid >> 3);
    const int brow = (swz >> 5) * FBM;
    const int bcol = (swz & 31) * FBM;
    const int wr = wid >> 1, wc = wid & 1;
    const float alpha = *alphap;
    const float beta  = *betap;

    int32x4 acc[4][4] = {};
    for (int kt = 0; kt < IN_DIM / FBK; ++kt) {
        const int64_t kbase = (int64_t)kt * FBK;
#pragma unroll
        for (int q = 0; q < 4; ++q) {
            const int off = wid * 4096 + q * 1024 + lane * 16;
            const int row = off >> 7;
            const int k   = off & 127;
            const int* ga = x32 + (int64_t)(brow + row) * IN_DIM + kbase + k;
            const int* gb = w32 + (int64_t)(bcol + row) * IN_DIM + kbase + k;
            uint32_t pa[4], pb[4];
#pragma unroll
            for (int v = 0; v < 4; ++v) {
                int32x4 ta = reinterpret_cast<const int32x4*>(ga)[v];
                int32x4 tb = reinterpret_cast<const int32x4*>(gb)[v];
                pa[v] = (uint32_t)(ta[0] & 0xff) | ((uint32_t)(ta[1] & 0xff) << 8) |
                        ((uint32_t)(ta[2] & 0xff) << 16) | ((uint32_t)(ta[3] & 0xff) << 24);
                pb[v] = (uint32_t)(tb[0] & 0xff) | ((uint32_t)(tb[1] & 0xff) << 8) |
                        ((uint32_t)(tb[2] & 0xff) << 16) | ((uint32_t)(tb[3] & 0xff) << 24);
            }
            const int sc = ((k >> 4) ^ (row & 7)) << 4;
            *reinterpret_cast<int32x4*>(lA + row * FBK + sc) = *reinterpret_cast<int32x4*>(pa);
            *reinterpret_cast<int32x4*>(lB + row * FBK + sc) = *reinterpret_cast<int32x4*>(pb);
        }
        __syncthreads();
#pragma unroll
        for (int ks = 0; ks < 2; ++ks) {
            const int gg = lane >> 4, rr = lane & 15;
            const int lc = ks * 4 + gg;
            int32x4 af[4], bf[4];
#pragma unroll
            for (int m = 0; m < 4; ++m) {
                const int row = wr * 64 + m * 16 + rr;
                af[m] = *reinterpret_cast<const int32x4*>(lA + row * FBK + ((lc ^ (row & 7)) << 4));
            }
#pragma unroll
            for (int n = 0; n < 4; ++n) {
                const int row = wc * 64 + n * 16 + rr;
                bf[n] = *reinterpret_cast<const int32x4*>(lB + row * FBK + ((lc ^ (row & 7)) << 4));
            }
#pragma unroll
            for (int m = 0; m < 4; ++m)
#pragma unroll
                for (int n = 0; n < 4; ++n)
                    acc[m][n] = __builtin_amdgcn_mfma_i32_16x16x64_i8(af[m], bf[n], acc[m][n], 0, 0, 0);
        }
        __syncthreads();
    }
    const int r4 = (lane >> 4) * 4;
    const int cl = lane & 15;
#pragma unroll
    for (int n = 0; n < 4; ++n) {
        const int col = bcol + wc * 64 + n * 16 + cl;
        const float bterm = (float)bias[col] * beta;
#pragma unroll
        for (int m = 0; m < 4; ++m) {
            const int row0 = brow + wr * 64 + m * 16 + r4;
#pragma unroll
            for (int j = 0; j < 4; ++j) {
                float y = (float)acc[m][n][j] * alpha + bterm;
                y = rintf(y);
                y = fminf(fmaxf(y, -128.0f), 127.0f);
                out[(int64_t)(row0 + j) * OUT_DIM + col] = (int)y;
            }
        }
    }
}

// ===========================================================================
extern "C" void kernel_launch(void* const* d_in, const int* in_sizes, int n_in,
                              void* d_out, int out_size, void* d_ws, size_t ws_size,
                              hipStream_t stream) {
    const int*   x     = (const int*)d_in[0];
    const int*   w     = (const int*)d_in[1];
    const int*   bias  = (const int*)d_in[2];
    const float* alpha = (const float*)d_in[3];
    const float* beta  = (const float*)d_in[4];
    int*         out   = (int*)d_out;

    const size_t need = (size_t)T_DIM * IN_DIM + (size_t)OUT_DIM * IN_DIM;

    if (ws_size >= need) {
        int8_t* x8 = (int8_t*)d_ws;
        int8_t* w8 = x8 + (size_t)T_DIM * IN_DIM;
        {
            int64_t nch = (int64_t)T_DIM * (IN_DIM / 16);
            pack_swz<<<(int)((nch + 255) / 256), 256, 0, stream>>>(x, x8, T_DIM, IN_DIM);
        }
        {
            int64_t nch = (int64_t)OUT_DIM * (IN_DIM / 16);
            pack_swz<<<(int)((nch + 255) / 256), 256, 0, stream>>>(w, w8, OUT_DIM, IN_DIM);
        }
        const int grid = (T_DIM / BM) * (OUT_DIM / BN);  // 1024
        gemm_i8_8p<<<grid, 512, 0, stream>>>(x8, w8, bias, alpha, beta, out);
    } else {
        const int grid = (T_DIM / 128) * (OUT_DIM / 128);  // 4096
        gemm_i8_fb<<<grid, 256, 0, stream>>>(x, w, bias, alpha, beta, out);
    }
}